// Round 18
// baseline (230.285 us; speedup 1.0000x reference)
//
#include <hip/hip_runtime.h>
#include <hip/hip_bf16.h>

// Problem constants: B=2, S=2048, D=2048, H=32, KVH=8, HD=64, N_REP=4
#define BB 2
#define SS 2048
#define DD 2048
#define HH 32
#define KVH 8
#define HD 64
#define QKV_LD 3072   // Q(2048) | K(512) | V(512)

typedef unsigned short u16;
typedef unsigned int u32;
typedef __attribute__((ext_vector_type(8))) short s16x8;   // bf16x8 MFMA fragment (4 VGPRs)
typedef __attribute__((ext_vector_type(4))) float f32x4;   // MFMA accumulator
typedef __attribute__((ext_vector_type(4))) u16 u16x4;
typedef __attribute__((ext_vector_type(2))) u32 u32x2;
typedef __attribute__((ext_vector_type(4))) u32 u32x4;

#define MFMA(a, b, c) __builtin_amdgcn_mfma_f32_16x16x32_bf16((a), (b), (c), 0, 0, 0)

__device__ __forceinline__ u16 f2bf(float f) {
  union { float f; u32 u; } x; x.f = f;
  u32 r = x.u + 0x7fffu + ((x.u >> 16) & 1u);  // round-to-nearest-even
  return (u16)(r >> 16);
}
__device__ __forceinline__ float bf2f(u32 u) {
  union { u32 u; float f; } x; x.u = u << 16;
  return x.f;
}
// HW packed f32x2 -> bf16x2 (RTNE), lo=a, hi=b
__device__ __forceinline__ u32 cvtpk(float a, float b) {
  u32 r;
  asm("v_cvt_pk_bf16_f32 %0, %1, %2" : "=v"(r) : "v"(a), "v"(b));
  return r;
}

// async global->LDS, 16B per lane. dest must be (wave-uniform base + lane*16).
__device__ __forceinline__ void gload16(const void* g, void* l) {
  __builtin_amdgcn_global_load_lds((const __attribute__((address_space(1))) unsigned int*)g,
                                   (__attribute__((address_space(3))) unsigned int*)l, 16, 0, 0);
}

// Read one bf16x8 MFMA fragment from a [rows][64] bf16 LDS tile with the
// G4 XOR swizzle (16B block index ^= row&7). c = 16B-block index (k/8).
__device__ __forceinline__ s16x8 lds_frag(const u16* base, int row, int c) {
  return *(const s16x8*)(base + (row << 6) + (((c ^ (row & 7)) << 3)));
}

// Same fragment from a [rows][64] FP32 LDS tile (row = 256B = 8 granules of
// 32B). Swizzle: granule ^= row&7 AND 16B-half ^= (row>>3)&1 — spreads 16
// lanes over all 32 banks at 2-way (free); granule-only was 4-way (round-17
// ERRATA: 12.6M conflicts). Converts to bf16 in-reg via cvt_pk.
__device__ __forceinline__ s16x8 lds_frag_f32(const float* base, int row, int c) {
  const int hb = (row >> 3) & 1;
  const char* p = (const char*)base + (row << 8) + ((c ^ (row & 7)) << 5);
  f32x4 lo = *(const f32x4*)(p + (hb << 4));
  f32x4 hi = *(const f32x4*)(p + ((1 ^ hb) << 4));
  union { u32x4 u; s16x8 s; } r;
  r.u[0] = cvtpk(lo[0], lo[1]);
  r.u[1] = cvtpk(lo[2], lo[3]);
  r.u[2] = cvtpk(hi[0], hi[1]);
  r.u[3] = cvtpk(hi[2], hi[3]);
  return r.s;
}

// ---------------------------------------------------------------------------
// transpose-cast: dst[c*dld + r] = bf16(src[r*scols + c]); grid (scols/32, srows/32), block (32,8)
__global__ void tcast(const float* __restrict__ src, int scols, u16* __restrict__ dst, int dld) {
  __shared__ float tt[32][33];
  int c0 = blockIdx.x << 5, r0 = blockIdx.y << 5;
  int tx = threadIdx.x, ty = threadIdx.y;
#pragma unroll
  for (int j = 0; j < 4; ++j)
    tt[ty + j * 8][tx] = src[(size_t)(r0 + ty + j * 8) * scols + c0 + tx];
  __syncthreads();
#pragma unroll
  for (int j = 0; j < 4; ++j)
    dst[(size_t)(c0 + ty + j * 8) * dld + r0 + tx] = f2bf(tt[tx][ty + j * 8]);
}

// RoPE in-place on Q cols [0,2048) and K cols [2048,2560) of qkv [4096][3072].
// 4 pairs (16B) per thread, HW cvt_pk. Q pre-scaled by 1/sqrt(HD)*log2(e).
__global__ void rope_k(u16* __restrict__ qkv, const float* __restrict__ fc, const float* __restrict__ fs) {
  const float SCLQ = 0.125f * 1.44269504f;
  int idx = blockIdx.x * 256 + threadIdx.x;          // 4096*320 total
  int row = idx / 320;
  int p4 = (idx - row * 320) << 2;                   // pair index, multiple of 4
  int s = row & (SS - 1);
  int col, i;
  float sc;
  if (p4 < 1024) { col = p4 << 1; i = p4 & 31; sc = SCLQ; }
  else { int pk = p4 - 1024; col = 2048 + (pk << 1); i = pk & 31; sc = 1.0f; }
  size_t base = (size_t)row * QKV_LD + col;
  u32x4 v = *(const u32x4*)(qkv + base);
  const float4 c4 = *(const float4*)(fc + s * 32 + i);
  const float4 s4 = *(const float4*)(fs + s * 32 + i);
  float cc[4] = {c4.x, c4.y, c4.z, c4.w};
  float ss[4] = {s4.x, s4.y, s4.z, s4.w};
  u32x4 o;
#pragma unroll
  for (int j = 0; j < 4; ++j) {
    float t1 = bf2f(v[j] & 0xffffu), t2 = bf2f(v[j] >> 16);
    float r1 = (t1 * cc[j] - t2 * ss[j]) * sc;
    float r2 = (t1 * ss[j] + t2 * cc[j]) * sc;
    o[j] = cvtpk(r1, r2);
  }
  *(u32x4*)(qkv + base) = o;
}

// V part of qkv (cols [2560,3072)) -> vt[((b*8+g)*64 + d)*2048 + s]
__global__ void transpose_v(const u16* __restrict__ qkv, u16* __restrict__ vt) {
  __shared__ u16 tt[32][33];
  int c0 = blockIdx.x << 5, r0 = blockIdx.y << 5;   // c0: V col, r0: b*S+s row
  int tx = threadIdx.x, ty = threadIdx.y;
#pragma unroll
  for (int j = 0; j < 4; ++j)
    tt[ty + j * 8][tx] = qkv[(size_t)(r0 + ty + j * 8) * QKV_LD + 2560 + c0 + tx];
  __syncthreads();
#pragma unroll
  for (int j = 0; j < 4; ++j) {
    int c = c0 + ty + j * 8;              // V column -> (g,d)
    int rr = r0 + tx;                     // source row -> (b,s)
    int b = rr >> 11, s = rr & (SS - 1), g = c >> 6, d = c & 63;
    vt[(size_t)((((b << 3) + g) << 6) + d) * SS + s] = tt[tx][ty + j * 8];
  }
}

// ---------------------------------------------------------------------------
// C[M][N] = A[M][K] @ BT[N][K]^T   (fp32 acc), lda == K.
// 128x128 tile, BK=64, EIGHT waves (2m x 4n, each 64x32), 512 threads.
// AF32: A staged as RAW FP32 via async global_load_lds (32KB tile; granule+
// half XOR swizzle, pre-applied to the DMA source, inverted on read) and
// converted to bf16 on the LDS->reg side. SWZ: chunked XCD swizzle.
// Cf!=null: fp32 out + bias. else bf16 out.
template<bool AF32, bool SWZ>
__global__ __launch_bounds__(512, 2) void gemm_bt(const u16* __restrict__ A, const float* __restrict__ Af,
                                                  const u16* __restrict__ BT,
                                                  int K, u16* __restrict__ Cb, float* __restrict__ Cf,
                                                  const float* __restrict__ bias, int ldc) {
  __shared__ alignas(16) u16 lds[AF32 ? 3 * 128 * 64 : 2 * 128 * 64];
  u16* Bl = lds;                            // 16KB B tile (bf16)
  u16* Al = lds + 128 * 64;                 // 16KB A tile (bf16, !AF32)
  float* AlF = (float*)(lds + 128 * 64);    // 32KB A tile (fp32, AF32)
  const int t = threadIdx.x, w = t >> 6, lane = t & 63;
  const int q_l = lane & 15, gh = lane >> 4;
  int m0, n0;
  if constexpr (SWZ) {
    const int gx = gridDim.x, nxy = gx * gridDim.y;
    int xy = blockIdx.y * gx + blockIdx.x;
    xy = (xy & 7) * (nxy >> 3) + (xy >> 3);     // bijective when nxy % 8 == 0
    n0 = (xy % gx) << 7;
    m0 = (xy / gx) << 7;
  } else {
    m0 = blockIdx.y << 7;
    n0 = blockIdx.x << 7;
  }
  const int wm = (w >> 2) << 6;        // 0 or 64
  const int wn = (w & 3) << 5;         // 0,32,64,96
  f32x4 acc[4][2] = {};

  for (int k0 = 0; k0 < K; k0 += 64) {
    // B: 2 chunks of 8KB, 16B-block swizzle via pre-swizzled source
#pragma unroll
    for (int i = 0; i < 2; ++i) {
      int o = (i << 13) + (t << 4);
      int row = o >> 7;
      int sblk = ((o >> 4) & 7) ^ (row & 7);
      gload16((const char*)BT + (((size_t)(n0 + row) * K + k0) << 1) + (sblk << 4), (char*)Bl + o);
    }
    if constexpr (AF32) {
      // A fp32: 4 chunks of 8KB; granule+half swizzle pre-applied to source.
      // byte b: row = b>>8 (256B rows), granule = (b>>5)&7, half = (b>>4)&1.
#pragma unroll
      for (int j = 0; j < 4; ++j) {
        int b = (j << 13) + (t << 4);
        int row = b >> 8;
        int gsrc = ((b >> 5) & 7) ^ (row & 7);
        int hsrc = ((b >> 4) & 1) ^ ((row >> 3) & 1);
        gload16(Af + (size_t)(m0 + row) * K + k0 + (gsrc << 3) + (hsrc << 2), (char*)AlF + b);
      }
    } else {
#pragma unroll
      for (int i = 0; i < 2; ++i) {
        int o = (i << 13) + (t << 4);
        int row = o >> 7;
        int sblk = ((o >> 4) & 7) ^ (row & 7);
        gload16((const char*)A + (((size_t)(m0 + row) * K + k0) << 1) + (sblk << 4), (char*)Al + o);
      }
    }
    __syncthreads();

#pragma unroll
    for (int kk = 0; kk < 64; kk += 32) {
      const int c = (kk >> 3) + gh;
      s16x8 af[4], bfr[2];
#pragma unroll
      for (int mi = 0; mi < 4; ++mi) {
        if constexpr (AF32) af[mi] = lds_frag_f32(AlF, wm + (mi << 4) + q_l, c);
        else af[mi] = lds_frag(Al, wm + (mi << 4) + q_l, c);
      }
#pragma unroll
      for (int ni = 0; ni < 2; ++ni) bfr[ni] = lds_frag(Bl, wn + (ni << 4) + q_l, c);
#pragma unroll
      for (int mi = 0; mi < 4; ++mi)
#pragma unroll
        for (int ni = 0; ni < 2; ++ni)
          acc[mi][ni] = MFMA(af[mi], bfr[ni], acc[mi][ni]);
    }
    __syncthreads();
  }

  const int rbase = m0 + wm + (gh << 2);
  const int cbase = n0 + wn + q_l;
  if (Cf != nullptr) {
#pragma unroll
    for (int mi = 0; mi < 4; ++mi)
#pragma unroll
      for (int ni = 0; ni < 2; ++ni) {
        int col = cbase + (ni << 4);
        float bv = bias[col];
#pragma unroll
        for (int r = 0; r < 4; ++r)
          Cf[(size_t)(rbase + (mi << 4) + r) * ldc + col] = acc[mi][ni][r] + bv;
      }
  } else {
#pragma unroll
    for (int mi = 0; mi < 4; ++mi)
#pragma unroll
      for (int ni = 0; ni < 2; ++ni) {
        int col = cbase + (ni << 4);
#pragma unroll
        for (int r = 0; r < 4; ++r)
          Cb[(size_t)(rbase + (mi << 4) + r) * ldc + col] = f2bf(acc[mi][ni][r]);
      }
  }
}

// ---------------------------------------------------------------------------
// Flash attention v9: swapped-operand QK^T + ones-MFMA l + max3 tree +
// reg-staged prefetch + double-buffered K/V (one barrier per tile) +
// balanced LPT. __launch_bounds__(256,4) pins regalloc (no spills).
__global__ __launch_bounds__(256, 4) void attn_k(const u16* __restrict__ qkv, const u16* __restrict__ vt,
                                                 u16* __restrict__ ctx) {
  __shared__ alignas(16) u16 sK[2][64 * 64];
  __shared__ alignas(16) u16 sV[2][64 * 64];
  __shared__ alignas(16) u16 sP[4][16 * 64];
  const int bid = blockIdx.x;
  const int qt = 31 - (bid >> 6);                 // balanced + LPT
  const int h = bid & 31, b = (bid >> 5) & 1;
  const int q0 = qt << 6, g = h >> 2;
  const int t = threadIdx.x, w = t >> 6, lane = t & 63;
  const int q_l = lane & 15, gh = lane >> 4;

  // all-ones bf16 fragment for the l-row MFMA
  const s16x8 ones = { (short)0x3F80, (short)0x3F80, (short)0x3F80, (short)0x3F80,
                       (short)0x3F80, (short)0x3F80, (short)0x3F80, (short)0x3F80 };

  // staging geometry: chunk i in 0..1, row = (i<<5) + (w<<3) + (lane>>3), blk = lane&7.
  const int srow = (w << 3) + (lane >> 3);        // row within chunk 0 (0..31)
  const int blk = lane & 7;                       // 16B block within 64-u16 row
  const int lw0 = (srow << 6) + ((blk ^ (lane >> 3)) << 3);   // row&7 == lane>>3
  const u16* kg = qkv + (size_t)((b << 11) + srow) * QKV_LD + 2048 + (g << 6) + (blk << 3);
  const u16* vg = vt + (size_t)((((b << 3) + g) << 6) + srow) * SS + (blk << 3);

  // Q fragment (B-frag for swapped QK: lane holds Q[q=lane&15][d=8*gh+e])
  const int qrow = (b << 11) + q0 + (w << 4) + q_l;
  const u16* qptr = qkv + (size_t)qrow * QKV_LD + (h << 6) + (gh << 3);
  s16x8 qa0 = *(const s16x8*)qptr;
  s16x8 qa1 = *(const s16x8*)(qptr + 32);

  f32x4 o[4] = {};
  f32x4 lacc = {};                                // l[q] in every reg (ones-row MFMA)
  float m1 = -INFINITY;
  const int myq = q0 + (w << 4) + q_l;            // this lane's q row

  // prologue: tile 0 regs -> LDS buf0 -> barrier
  s16x8 kr[2], vr[2];
#pragma unroll
  for (int i = 0; i < 2; ++i) {
    kr[i] = *(const s16x8*)(kg + (size_t)(i << 5) * QKV_LD);
    vr[i] = *(const s16x8*)(vg + (size_t)(i << 5) * SS);
  }
#pragma unroll
  for (int i = 0; i < 2; ++i) {
    *(s16x8*)(sK[0] + lw0 + (i << 11)) = kr[i];
    *(s16x8*)(sV[0] + lw0 + (i << 11)) = vr[i];
  }
  __syncthreads();

  for (int kt_i = 0; kt_i <= qt; ++kt_i) {
    const int k0 = kt_i << 6;
    const int cur = kt_i & 1;
    const u16* Kl = sK[cur];
    const u16* Vl = sV[cur];
    // issue next-tile global loads early; latency hides under this tile's compute
    if (kt_i < qt) {
      const int kn = k0 + 64;
#pragma unroll
      for (int i = 0; i < 2; ++i) {
        kr[i] = *(const s16x8*)(kg + (size_t)(kn + (i << 5)) * QKV_LD);
        vr[i] = *(const s16x8*)(vg + (size_t)(i << 5) * SS + kn);
      }
    }

    // S^T = K Q^T (64k x 16q per wave); lane: q = lane&15, k = nc*16 + gh*4 + r
    f32x4 sacc[4];
    __builtin_amdgcn_s_setprio(1);
#pragma unroll
    for (int nc = 0; nc < 4; ++nc) {
      f32x4 a = {};
      a = MFMA(lds_frag(Kl, (nc << 4) + q_l, gh), qa0, a);
      a = MFMA(lds_frag(Kl, (nc << 4) + q_l, 4 + gh), qa1, a);
      sacc[nc] = a;
    }
    __builtin_amdgcn_s_setprio(0);

    // causal mask on the diagonal tile only (Q already carries the scale)
    float pv[4][4];
    if (kt_i == qt) {
#pragma unroll
      for (int nc = 0; nc < 4; ++nc) {
        int kb = k0 + (nc << 4) + (gh << 2);
#pragma unroll
        for (int r = 0; r < 4; ++r) {
          float v = sacc[nc][r];
          if (kb + r > myq) v = -INFINITY;
          pv[nc][r] = v;
        }
      }
    } else {
#pragma unroll
      for (int nc = 0; nc < 4; ++nc)
#pragma unroll
        for (int r = 0; r < 4; ++r)
          pv[nc][r] = sacc[nc][r];
    }

    // lane-local tile max (max3-friendly tree) + defer-max check
    float ta = fmaxf(fmaxf(pv[0][0], pv[0][1]), pv[0][2]);
    float tb = fmaxf(fmaxf(pv[0][3], pv[1][0]), pv[1][1]);
    float tc = fmaxf(fmaxf(pv[1][2], pv[1][3]), pv[2][0]);
    float td = fmaxf(fmaxf(pv[2][1], pv[2][2]), pv[2][3]);
    float te = fmaxf(fmaxf(pv[3][0], pv[3][1]), pv[3][2]);
    float tmax = fmaxf(fmaxf(fmaxf(ta, tb), fmaxf(tc, td)), fmaxf(te, pv[3][3]));
    if (__any(tmax > m1 + 8.f)) {
      // row max over all 64 k (across the 4 lane-groups), uniform per q
      float rmax = tmax;
      rmax = fmaxf(rmax, __shfl_xor(rmax, 16));
      rmax = fmaxf(rmax, __shfl_xor(rmax, 32));
      float mn = fmaxf(m1, rmax);
      float alpha = exp2f(m1 - mn);
      m1 = mn;
#pragma unroll
      for (int r = 0; r < 4; ++r) lacc[r] *= alpha;
#pragma unroll
      for (int dc = 0; dc < 4; ++dc)
#pragma unroll
        for (int r = 0; r < 4; ++r) o[dc][r] *= alpha;
    }

    // P = exp2(S' - m)  (l comes from the ones-row MFMA below)
#pragma unroll
    for (int nc = 0; nc < 4; ++nc)
#pragma unroll
      for (int r = 0; r < 4; ++r)
        pv[nc][r] = exp2f(pv[nc][r] - m1);

    // P^T -> per-wave LDS [16 q][64 k], k-contiguous: one b64 per nc
    u16* pb = sP[w];
#pragma unroll
    for (int nc = 0; nc < 4; ++nc) {
      u32x2 pw;
      pw[0] = cvtpk(pv[nc][0], pv[nc][1]);
      pw[1] = cvtpk(pv[nc][2], pv[nc][3]);
      int byte = (q_l << 7) + (((((nc << 1) + (gh >> 1)) ^ (q_l & 7)) << 4)) + ((gh & 1) << 3);
      *(u32x2*)((char*)pb + byte) = pw;
    }
    asm volatile("s_waitcnt lgkmcnt(0)" ::: "memory");   // intra-wave P write->read
    __builtin_amdgcn_sched_barrier(0);

    // O^T += V^T P^T ; l += 1^T P^T (matrix pipe)
    s16x8 pa0 = lds_frag(pb, q_l, gh);
    s16x8 pa1 = lds_frag(pb, q_l, 4 + gh);
    __builtin_amdgcn_s_setprio(1);
#pragma unroll
    for (int dc = 0; dc < 4; ++dc) {
      o[dc] = MFMA(lds_frag(Vl, (dc << 4) + q_l, gh), pa0, o[dc]);
      o[dc] = MFMA(lds_frag(Vl, (dc << 4) + q_l, 4 + gh), pa1, o[dc]);
    }
    lacc = MFMA(ones, pa0, lacc);
    lacc = MFMA(ones, pa1, lacc);
    __builtin_amdgcn_s_setprio(0);

    // publish next tile into the other buffer (no WAR: nobody reads it now)
    if (kt_i < qt) {
#pragma unroll
      for (int i = 0; i < 2; ++i) {
        *(s16x8*)(sK[cur ^ 1] + lw0 + (i << 11)) = kr[i];
        *(s16x8*)(sV[cur ^ 1] + lw0 + (i << 11)) = vr[i];
      }
    }
    __syncthreads();                 // single rendezvous: closes reads + publishes writes
  }

  // epilogue: lacc[r] all hold l[q]; ctx row is fixed per lane (q)
  float inv = 1.0f / lacc[0];
  u16* crow = ctx + (size_t)((b << 11) + myq) * DD + (h << 6) + (gh << 2);
#pragma unroll
  for (int dc = 0; dc < 4; ++dc) {
    u32x2 ov;
    ov[0] = cvtpk(o[dc][0] * inv, o[dc][1] * inv);
    ov[1] = cvtpk(o[dc][2] * inv, o[dc][3] * inv);
    *(u32x2*)(crow + (dc << 4)) = ov;
  }
}

// ---------------------------------------------------------------------------
extern "C" void kernel_launch(void* const* d_in, const int* in_sizes, int n_in,
                              void* d_out, int out_size, void* d_ws, size_t ws_size,
                              hipStream_t stream) {
  const float* x  = (const float*)d_in[0];
  const float* Wq = (const float*)d_in[1];
  const float* Wk = (const float*)d_in[2];
  const float* Wv = (const float*)d_in[3];
  const float* Wo = (const float*)d_in[4];
  const float* bo = (const float*)d_in[5];
  const float* fc = (const float*)d_in[6];
  const float* fs = (const float*)d_in[7];
  float* out = (float*)d_out;

  // workspace layout (u16 units):
  u16* ws   = (u16*)d_ws;
  u16* ctx  = ws;                      // 8,388,608  (attn output, bf16)
  u16* wT   = ctx + 8388608;           // 6,291,456  (W_qkv^T; reused as W_o^T)
  u16* qkv  = wT + 6291456;            // 12,582,912 (Q|K|V, ld 3072)
  u16* vt   = qkv + 12582912;          // 2,097,152  (V^T per (b,g): [64][2048])
  u16* woT  = wT;

  dim3 b32(32, 8, 1);

  // 1. transpose-cast weights
  tcast<<<dim3(64, 64), b32, 0, stream>>>(Wq, 2048, wT, 2048);
  tcast<<<dim3(16, 64), b32, 0, stream>>>(Wk, 512, wT + (size_t)2048 * 2048, 2048);
  tcast<<<dim3(16, 64), b32, 0, stream>>>(Wv, 512, wT + (size_t)2560 * 2048, 2048);

  // 2. fused QKV projection (A = x fp32 staged raw via async global_load_lds,
  //    converted LDS->reg; XCD-chunked swizzle):
  //    [4096][2048] @ [3072][2048]^T -> qkv bf16
  gemm_bt<true, true><<<dim3(24, 32), 512, 0, stream>>>(nullptr, x, wT, 2048, qkv, nullptr, nullptr, QKV_LD);

  // 3. W_o^T
  tcast<<<dim3(64, 64), b32, 0, stream>>>(Wo, 2048, woT, 2048);

  // 4. RoPE on Q,K (Q pre-scaled, vectorized); transpose V
  rope_k<<<5120, 256, 0, stream>>>(qkv, fc, fs);
  transpose_v<<<dim3(16, 128), b32, 0, stream>>>(qkv, vt);

  // 5. flash attention -> ctx bf16 [4096][2048]
  attn_k<<<2048, 256, 0, stream>>>(qkv, vt, ctx);

  // 6. output projection + bias -> fp32 d_out
  gemm_bt<false, false><<<dim3(16, 32), 512, 0, stream>>>(ctx, nullptr, woT, 2048, nullptr, out, bo, 2048);
}

// Round 19
// 208.910 us; speedup vs baseline: 1.1023x; 1.1023x over previous
//
#include <hip/hip_runtime.h>
#include <hip/hip_bf16.h>

// Problem constants: B=2, S=2048, D=2048, H=32, KVH=8, HD=64, N_REP=4
#define BB 2
#define SS 2048
#define DD 2048
#define HH 32
#define KVH 8
#define HD 64
#define QKV_LD 3072   // Q(2048) | K(512) | V(512)

typedef unsigned short u16;
typedef unsigned int u32;
typedef __attribute__((ext_vector_type(8))) short s16x8;   // bf16x8 MFMA fragment (4 VGPRs)
typedef __attribute__((ext_vector_type(4))) float f32x4;   // MFMA accumulator
typedef __attribute__((ext_vector_type(4))) u16 u16x4;
typedef __attribute__((ext_vector_type(2))) u32 u32x2;
typedef __attribute__((ext_vector_type(4))) u32 u32x4;

#define MFMA(a, b, c) __builtin_amdgcn_mfma_f32_16x16x32_bf16((a), (b), (c), 0, 0, 0)

__device__ __forceinline__ u16 f2bf(float f) {
  union { float f; u32 u; } x; x.f = f;
  u32 r = x.u + 0x7fffu + ((x.u >> 16) & 1u);  // round-to-nearest-even
  return (u16)(r >> 16);
}
__device__ __forceinline__ float bf2f(u32 u) {
  union { u32 u; float f; } x; x.u = u << 16;
  return x.f;
}
// HW packed f32x2 -> bf16x2 (RTNE), lo=a, hi=b
__device__ __forceinline__ u32 cvtpk(float a, float b) {
  u32 r;
  asm("v_cvt_pk_bf16_f32 %0, %1, %2" : "=v"(r) : "v"(a), "v"(b));
  return r;
}

// async global->LDS, 16B per lane. dest must be (wave-uniform base + lane*16).
__device__ __forceinline__ void gload16(const void* g, void* l) {
  __builtin_amdgcn_global_load_lds((const __attribute__((address_space(1))) unsigned int*)g,
                                   (__attribute__((address_space(3))) unsigned int*)l, 16, 0, 0);
}

// Read one bf16x8 MFMA fragment from a [rows][64] bf16 LDS tile with the
// G4 XOR swizzle (16B block index ^= row&7). c = 16B-block index (k/8).
__device__ __forceinline__ s16x8 lds_frag(const u16* base, int row, int c) {
  return *(const s16x8*)(base + (row << 6) + (((c ^ (row & 7)) << 3)));
}

// ---------------------------------------------------------------------------
// cast fp32 -> bf16, 4 elems/thread, exact grid (at HBM roofline: 96MB/15us)
__global__ void cast_bf(const float* __restrict__ s, u16* __restrict__ d) {
  int i = blockIdx.x * 256 + threadIdx.x;
  float4 v = ((const float4*)s)[i];
  u16x4 o;
  o[0] = f2bf(v.x); o[1] = f2bf(v.y); o[2] = f2bf(v.z); o[3] = f2bf(v.w);
  ((u16x4*)d)[i] = o;
}

// transpose-cast: dst[c*dld + r] = bf16(src[r*scols + c]); grid (scols/32, srows/32), block (32,8)
__global__ void tcast(const float* __restrict__ src, int scols, u16* __restrict__ dst, int dld) {
  __shared__ float tt[32][33];
  int c0 = blockIdx.x << 5, r0 = blockIdx.y << 5;
  int tx = threadIdx.x, ty = threadIdx.y;
#pragma unroll
  for (int j = 0; j < 4; ++j)
    tt[ty + j * 8][tx] = src[(size_t)(r0 + ty + j * 8) * scols + c0 + tx];
  __syncthreads();
#pragma unroll
  for (int j = 0; j < 4; ++j)
    dst[(size_t)(c0 + ty + j * 8) * dld + r0 + tx] = f2bf(tt[tx][ty + j * 8]);
}

// RoPE in-place on Q cols [0,2048) and K cols [2048,2560) of qkv [4096][3072].
// 4 pairs (16B) per thread, HW cvt_pk. Q pre-scaled by 1/sqrt(HD)*log2(e).
__global__ void rope_k(u16* __restrict__ qkv, const float* __restrict__ fc, const float* __restrict__ fs) {
  const float SCLQ = 0.125f * 1.44269504f;
  int idx = blockIdx.x * 256 + threadIdx.x;          // 4096*320 total
  int row = idx / 320;
  int p4 = (idx - row * 320) << 2;                   // pair index, multiple of 4
  int s = row & (SS - 1);
  int col, i;
  float sc;
  if (p4 < 1024) { col = p4 << 1; i = p4 & 31; sc = SCLQ; }
  else { int pk = p4 - 1024; col = 2048 + (pk << 1); i = pk & 31; sc = 1.0f; }
  size_t base = (size_t)row * QKV_LD + col;
  u32x4 v = *(const u32x4*)(qkv + base);
  const float4 c4 = *(const float4*)(fc + s * 32 + i);
  const float4 s4 = *(const float4*)(fs + s * 32 + i);
  float cc[4] = {c4.x, c4.y, c4.z, c4.w};
  float ss[4] = {s4.x, s4.y, s4.z, s4.w};
  u32x4 o;
#pragma unroll
  for (int j = 0; j < 4; ++j) {
    float t1 = bf2f(v[j] & 0xffffu), t2 = bf2f(v[j] >> 16);
    float r1 = (t1 * cc[j] - t2 * ss[j]) * sc;
    float r2 = (t1 * ss[j] + t2 * cc[j]) * sc;
    o[j] = cvtpk(r1, r2);
  }
  *(u32x4*)(qkv + base) = o;
}

// V part of qkv (cols [2560,3072)) -> vt[((b*8+g)*64 + d)*2048 + s]
__global__ void transpose_v(const u16* __restrict__ qkv, u16* __restrict__ vt) {
  __shared__ u16 tt[32][33];
  int c0 = blockIdx.x << 5, r0 = blockIdx.y << 5;   // c0: V col, r0: b*S+s row
  int tx = threadIdx.x, ty = threadIdx.y;
#pragma unroll
  for (int j = 0; j < 4; ++j)
    tt[ty + j * 8][tx] = qkv[(size_t)(r0 + ty + j * 8) * QKV_LD + 2560 + c0 + tx];
  __syncthreads();
#pragma unroll
  for (int j = 0; j < 4; ++j) {
    int c = c0 + ty + j * 8;              // V column -> (g,d)
    int rr = r0 + tx;                     // source row -> (b,s)
    int b = rr >> 11, s = rr & (SS - 1), g = c >> 6, d = c & 63;
    vt[(size_t)((((b << 3) + g) << 6) + d) * SS + s] = tt[tx][ty + j * 8];
  }
}

// ---------------------------------------------------------------------------
// C[M][N] = A[M][K] @ BT[N][K]^T   (bf16 in, fp32 acc), lda == K.
// 128x128 tile, BK=64, EIGHT waves (2m x 4n, each 64x32), 512 threads.
// Cf!=null: fp32 out + bias. else bf16 out.
// (round-18 post-mortem: all four fused-fp32-A variants lost to this simple
//  bf16 path + separate cast; reverted for good.)
__global__ __launch_bounds__(512) void gemm_bt(const u16* __restrict__ A, const u16* __restrict__ BT,
                                               int K, u16* __restrict__ Cb, float* __restrict__ Cf,
                                               const float* __restrict__ bias, int ldc) {
  __shared__ alignas(16) u16 lds[2 * 128 * 64];
  u16* Al = lds;
  u16* Bl = lds + 128 * 64;
  const int t = threadIdx.x, w = t >> 6, lane = t & 63;
  const int q_l = lane & 15, gh = lane >> 4;
  const int m0 = blockIdx.y << 7, n0 = blockIdx.x << 7;
  const int wm = (w >> 2) << 6;        // 0 or 64
  const int wn = (w & 3) << 5;         // 0,32,64,96
  f32x4 acc[4][2] = {};

  for (int k0 = 0; k0 < K; k0 += 64) {
#pragma unroll
    for (int i = 0; i < 2; ++i) {
      int o = (i << 13) + (t << 4);                     // byte offset in 16KB tile
      int row = o >> 7;
      int cs = ((((o >> 4) & 7) ^ (row & 7)) << 4);     // pre-swizzled source block
      gload16((const char*)A + (((size_t)(m0 + row) * K + k0) << 1) + cs, (char*)Al + o);
      gload16((const char*)BT + (((size_t)(n0 + row) * K + k0) << 1) + cs, (char*)Bl + o);
    }
    __syncthreads();
#pragma unroll
    for (int kk = 0; kk < 64; kk += 32) {
      const int c = (kk >> 3) + gh;
      s16x8 af[4], bfr[2];
#pragma unroll
      for (int mi = 0; mi < 4; ++mi) af[mi] = lds_frag(Al, wm + (mi << 4) + q_l, c);
#pragma unroll
      for (int ni = 0; ni < 2; ++ni) bfr[ni] = lds_frag(Bl, wn + (ni << 4) + q_l, c);
#pragma unroll
      for (int mi = 0; mi < 4; ++mi)
#pragma unroll
        for (int ni = 0; ni < 2; ++ni)
          acc[mi][ni] = MFMA(af[mi], bfr[ni], acc[mi][ni]);
    }
    __syncthreads();
  }

  const int rbase = m0 + wm + (gh << 2);
  const int cbase = n0 + wn + q_l;
  if (Cf != nullptr) {
#pragma unroll
    for (int mi = 0; mi < 4; ++mi)
#pragma unroll
      for (int ni = 0; ni < 2; ++ni) {
        int col = cbase + (ni << 4);
        float bv = bias[col];
#pragma unroll
        for (int r = 0; r < 4; ++r)
          Cf[(size_t)(rbase + (mi << 4) + r) * ldc + col] = acc[mi][ni][r] + bv;
      }
  } else {
#pragma unroll
    for (int mi = 0; mi < 4; ++mi)
#pragma unroll
      for (int ni = 0; ni < 2; ++ni) {
        int col = cbase + (ni << 4);
#pragma unroll
        for (int r = 0; r < 4; ++r)
          Cb[(size_t)(rbase + (mi << 4) + r) * ldc + col] = f2bf(acc[mi][ni][r]);
      }
  }
}

// ---------------------------------------------------------------------------
// Flash attention v9: swapped-operand QK^T + ones-MFMA l + max3 tree +
// reg-staged prefetch + double-buffered K/V (one barrier per tile) +
// balanced LPT. __launch_bounds__(256,4) pins regalloc (no spills).
__global__ __launch_bounds__(256, 4) void attn_k(const u16* __restrict__ qkv, const u16* __restrict__ vt,
                                                 u16* __restrict__ ctx) {
  __shared__ alignas(16) u16 sK[2][64 * 64];
  __shared__ alignas(16) u16 sV[2][64 * 64];
  __shared__ alignas(16) u16 sP[4][16 * 64];
  const int bid = blockIdx.x;
  const int qt = 31 - (bid >> 6);                 // balanced + LPT
  const int h = bid & 31, b = (bid >> 5) & 1;
  const int q0 = qt << 6, g = h >> 2;
  const int t = threadIdx.x, w = t >> 6, lane = t & 63;
  const int q_l = lane & 15, gh = lane >> 4;

  // all-ones bf16 fragment for the l-row MFMA
  const s16x8 ones = { (short)0x3F80, (short)0x3F80, (short)0x3F80, (short)0x3F80,
                       (short)0x3F80, (short)0x3F80, (short)0x3F80, (short)0x3F80 };

  // staging geometry: chunk i in 0..1, row = (i<<5) + (w<<3) + (lane>>3), blk = lane&7.
  const int srow = (w << 3) + (lane >> 3);        // row within chunk 0 (0..31)
  const int blk = lane & 7;                       // 16B block within 64-u16 row
  const int lw0 = (srow << 6) + ((blk ^ (lane >> 3)) << 3);   // row&7 == lane>>3
  const u16* kg = qkv + (size_t)((b << 11) + srow) * QKV_LD + 2048 + (g << 6) + (blk << 3);
  const u16* vg = vt + (size_t)((((b << 3) + g) << 6) + srow) * SS + (blk << 3);

  // Q fragment (B-frag for swapped QK: lane holds Q[q=lane&15][d=8*gh+e])
  const int qrow = (b << 11) + q0 + (w << 4) + q_l;
  const u16* qptr = qkv + (size_t)qrow * QKV_LD + (h << 6) + (gh << 3);
  s16x8 qa0 = *(const s16x8*)qptr;
  s16x8 qa1 = *(const s16x8*)(qptr + 32);

  f32x4 o[4] = {};
  f32x4 lacc = {};                                // l[q] in every reg (ones-row MFMA)
  float m1 = -INFINITY;
  const int myq = q0 + (w << 4) + q_l;            // this lane's q row

  // prologue: tile 0 regs -> LDS buf0 -> barrier
  s16x8 kr[2], vr[2];
#pragma unroll
  for (int i = 0; i < 2; ++i) {
    kr[i] = *(const s16x8*)(kg + (size_t)(i << 5) * QKV_LD);
    vr[i] = *(const s16x8*)(vg + (size_t)(i << 5) * SS);
  }
#pragma unroll
  for (int i = 0; i < 2; ++i) {
    *(s16x8*)(sK[0] + lw0 + (i << 11)) = kr[i];
    *(s16x8*)(sV[0] + lw0 + (i << 11)) = vr[i];
  }
  __syncthreads();

  for (int kt_i = 0; kt_i <= qt; ++kt_i) {
    const int k0 = kt_i << 6;
    const int cur = kt_i & 1;
    const u16* Kl = sK[cur];
    const u16* Vl = sV[cur];
    // issue next-tile global loads early; latency hides under this tile's compute
    if (kt_i < qt) {
      const int kn = k0 + 64;
#pragma unroll
      for (int i = 0; i < 2; ++i) {
        kr[i] = *(const s16x8*)(kg + (size_t)(kn + (i << 5)) * QKV_LD);
        vr[i] = *(const s16x8*)(vg + (size_t)(i << 5) * SS + kn);
      }
    }

    // S^T = K Q^T (64k x 16q per wave); lane: q = lane&15, k = nc*16 + gh*4 + r
    f32x4 sacc[4];
    __builtin_amdgcn_s_setprio(1);
#pragma unroll
    for (int nc = 0; nc < 4; ++nc) {
      f32x4 a = {};
      a = MFMA(lds_frag(Kl, (nc << 4) + q_l, gh), qa0, a);
      a = MFMA(lds_frag(Kl, (nc << 4) + q_l, 4 + gh), qa1, a);
      sacc[nc] = a;
    }
    __builtin_amdgcn_s_setprio(0);

    // causal mask on the diagonal tile only (Q already carries the scale)
    float pv[4][4];
    if (kt_i == qt) {
#pragma unroll
      for (int nc = 0; nc < 4; ++nc) {
        int kb = k0 + (nc << 4) + (gh << 2);
#pragma unroll
        for (int r = 0; r < 4; ++r) {
          float v = sacc[nc][r];
          if (kb + r > myq) v = -INFINITY;
          pv[nc][r] = v;
        }
      }
    } else {
#pragma unroll
      for (int nc = 0; nc < 4; ++nc)
#pragma unroll
        for (int r = 0; r < 4; ++r)
          pv[nc][r] = sacc[nc][r];
    }

    // lane-local tile max (max3-friendly tree) + defer-max check
    float ta = fmaxf(fmaxf(pv[0][0], pv[0][1]), pv[0][2]);
    float tb = fmaxf(fmaxf(pv[0][3], pv[1][0]), pv[1][1]);
    float tc = fmaxf(fmaxf(pv[1][2], pv[1][3]), pv[2][0]);
    float td = fmaxf(fmaxf(pv[2][1], pv[2][2]), pv[2][3]);
    float te = fmaxf(fmaxf(pv[3][0], pv[3][1]), pv[3][2]);
    float tmax = fmaxf(fmaxf(fmaxf(ta, tb), fmaxf(tc, td)), fmaxf(te, pv[3][3]));
    if (__any(tmax > m1 + 8.f)) {
      // row max over all 64 k (across the 4 lane-groups), uniform per q
      float rmax = tmax;
      rmax = fmaxf(rmax, __shfl_xor(rmax, 16));
      rmax = fmaxf(rmax, __shfl_xor(rmax, 32));
      float mn = fmaxf(m1, rmax);
      float alpha = exp2f(m1 - mn);
      m1 = mn;
#pragma unroll
      for (int r = 0; r < 4; ++r) lacc[r] *= alpha;
#pragma unroll
      for (int dc = 0; dc < 4; ++dc)
#pragma unroll
        for (int r = 0; r < 4; ++r) o[dc][r] *= alpha;
    }

    // P = exp2(S' - m)  (l comes from the ones-row MFMA below)
#pragma unroll
    for (int nc = 0; nc < 4; ++nc)
#pragma unroll
      for (int r = 0; r < 4; ++r)
        pv[nc][r] = exp2f(pv[nc][r] - m1);

    // P^T -> per-wave LDS [16 q][64 k], k-contiguous: one b64 per nc
    u16* pb = sP[w];
#pragma unroll
    for (int nc = 0; nc < 4; ++nc) {
      u32x2 pw;
      pw[0] = cvtpk(pv[nc][0], pv[nc][1]);
      pw[1] = cvtpk(pv[nc][2], pv[nc][3]);
      int byte = (q_l << 7) + (((((nc << 1) + (gh >> 1)) ^ (q_l & 7)) << 4)) + ((gh & 1) << 3);
      *(u32x2*)((char*)pb + byte) = pw;
    }
    asm volatile("s_waitcnt lgkmcnt(0)" ::: "memory");   // intra-wave P write->read
    __builtin_amdgcn_sched_barrier(0);

    // O^T += V^T P^T ; l += 1^T P^T (matrix pipe)
    s16x8 pa0 = lds_frag(pb, q_l, gh);
    s16x8 pa1 = lds_frag(pb, q_l, 4 + gh);
    __builtin_amdgcn_s_setprio(1);
#pragma unroll
    for (int dc = 0; dc < 4; ++dc) {
      o[dc] = MFMA(lds_frag(Vl, (dc << 4) + q_l, gh), pa0, o[dc]);
      o[dc] = MFMA(lds_frag(Vl, (dc << 4) + q_l, 4 + gh), pa1, o[dc]);
    }
    lacc = MFMA(ones, pa0, lacc);
    lacc = MFMA(ones, pa1, lacc);
    __builtin_amdgcn_s_setprio(0);

    // publish next tile into the other buffer (no WAR: nobody reads it now)
    if (kt_i < qt) {
#pragma unroll
      for (int i = 0; i < 2; ++i) {
        *(s16x8*)(sK[cur ^ 1] + lw0 + (i << 11)) = kr[i];
        *(s16x8*)(sV[cur ^ 1] + lw0 + (i << 11)) = vr[i];
      }
    }
    __syncthreads();                 // single rendezvous: closes reads + publishes writes
  }

  // epilogue: lacc[r] all hold l[q]; ctx row is fixed per lane (q)
  float inv = 1.0f / lacc[0];
  u16* crow = ctx + (size_t)((b << 11) + myq) * DD + (h << 6) + (gh << 2);
#pragma unroll
  for (int dc = 0; dc < 4; ++dc) {
    u32x2 ov;
    ov[0] = cvtpk(o[dc][0] * inv, o[dc][1] * inv);
    ov[1] = cvtpk(o[dc][2] * inv, o[dc][3] * inv);
    *(u32x2*)(crow + (dc << 4)) = ov;
  }
}

// ---------------------------------------------------------------------------
extern "C" void kernel_launch(void* const* d_in, const int* in_sizes, int n_in,
                              void* d_out, int out_size, void* d_ws, size_t ws_size,
                              hipStream_t stream) {
  const float* x  = (const float*)d_in[0];
  const float* Wq = (const float*)d_in[1];
  const float* Wk = (const float*)d_in[2];
  const float* Wv = (const float*)d_in[3];
  const float* Wo = (const float*)d_in[4];
  const float* bo = (const float*)d_in[5];
  const float* fc = (const float*)d_in[6];
  const float* fs = (const float*)d_in[7];
  float* out = (float*)d_out;

  // workspace layout (u16 units):
  u16* ws   = (u16*)d_ws;
  u16* xb   = ws;                      // 8,388,608  (x bf16; reused as ctx)
  u16* wT   = xb + 8388608;            // 6,291,456  (W_qkv^T; reused as W_o^T)
  u16* qkv  = wT + 6291456;            // 12,582,912 (Q|K|V, ld 3072)
  u16* vt   = qkv + 12582912;          // 2,097,152  (V^T per (b,g): [64][2048])
  u16* ctx  = xb;
  u16* woT  = wT;

  dim3 b32(32, 8, 1);

  // 1. casts / transposes of weights + x
  cast_bf<<<8192, 256, 0, stream>>>(x, xb);
  tcast<<<dim3(64, 64), b32, 0, stream>>>(Wq, 2048, wT, 2048);
  tcast<<<dim3(16, 64), b32, 0, stream>>>(Wk, 512, wT + (size_t)2048 * 2048, 2048);
  tcast<<<dim3(16, 64), b32, 0, stream>>>(Wv, 512, wT + (size_t)2560 * 2048, 2048);

  // 2. fused QKV projection: [4096][2048] @ [3072][2048]^T -> qkv bf16
  gemm_bt<<<dim3(24, 32), 512, 0, stream>>>(xb, wT, 2048, qkv, nullptr, nullptr, QKV_LD);

  // 3. W_o^T
  tcast<<<dim3(64, 64), b32, 0, stream>>>(Wo, 2048, woT, 2048);

  // 4. RoPE on Q,K (Q pre-scaled, vectorized); transpose V
  rope_k<<<5120, 256, 0, stream>>>(qkv, fc, fs);
  transpose_v<<<dim3(16, 128), b32, 0, stream>>>(qkv, vt);

  // 5. flash attention -> ctx bf16 [4096][2048]
  attn_k<<<2048, 256, 0, stream>>>(qkv, vt, ctx);

  // 6. output projection + bias -> fp32 d_out
  gemm_bt<<<dim3(16, 32), 512, 0, stream>>>(ctx, woT, 2048, nullptr, out, bo, 2048);
}

// Round 20
// 206.495 us; speedup vs baseline: 1.1152x; 1.0117x over previous
//
#include <hip/hip_runtime.h>
#include <hip/hip_bf16.h>

// Problem constants: B=2, S=2048, D=2048, H=32, KVH=8, HD=64, N_REP=4
#define BB 2
#define SS 2048
#define DD 2048
#define HH 32
#define KVH 8
#define HD 64
#define QKV_LD 3072   // Q(2048) | K(512) | V(512)

typedef unsigned short u16;
typedef unsigned int u32;
typedef __attribute__((ext_vector_type(8))) short s16x8;   // bf16x8 MFMA fragment (4 VGPRs)
typedef __attribute__((ext_vector_type(4))) float f32x4;   // MFMA accumulator
typedef __attribute__((ext_vector_type(4))) u16 u16x4;
typedef __attribute__((ext_vector_type(2))) u32 u32x2;

#define MFMA(a, b, c) __builtin_amdgcn_mfma_f32_16x16x32_bf16((a), (b), (c), 0, 0, 0)

__device__ __forceinline__ u16 f2bf(float f) {
  union { float f; u32 u; } x; x.f = f;
  u32 r = x.u + 0x7fffu + ((x.u >> 16) & 1u);  // round-to-nearest-even
  return (u16)(r >> 16);
}
__device__ __forceinline__ float bf2f(u32 u) {
  union { u32 u; float f; } x; x.u = u << 16;
  return x.f;
}
// HW packed f32x2 -> bf16x2 (RTNE), lo=a, hi=b
__device__ __forceinline__ u32 cvtpk(float a, float b) {
  u32 r;
  asm("v_cvt_pk_bf16_f32 %0, %1, %2" : "=v"(r) : "v"(a), "v"(b));
  return r;
}

// async global->LDS, 16B per lane. dest must be (wave-uniform base + lane*16).
__device__ __forceinline__ void gload16(const void* g, void* l) {
  __builtin_amdgcn_global_load_lds((const __attribute__((address_space(1))) unsigned int*)g,
                                   (__attribute__((address_space(3))) unsigned int*)l, 16, 0, 0);
}

// Read one bf16x8 MFMA fragment from a [rows][64] bf16 LDS tile with the
// G4 XOR swizzle (16B block index ^= row&7). c = 16B-block index (k/8).
__device__ __forceinline__ s16x8 lds_frag(const u16* base, int row, int c) {
  return *(const s16x8*)(base + (row << 6) + (((c ^ (row & 7)) << 3)));
}

// ---------------------------------------------------------------------------
// cast fp32 -> bf16, 4 elems/thread, exact grid (at HBM roofline: 96MB/15us)
__global__ void cast_bf(const float* __restrict__ s, u16* __restrict__ d) {
  int i = blockIdx.x * 256 + threadIdx.x;
  float4 v = ((const float4*)s)[i];
  u16x4 o;
  o[0] = f2bf(v.x); o[1] = f2bf(v.y); o[2] = f2bf(v.z); o[3] = f2bf(v.w);
  ((u16x4*)d)[i] = o;
}

// transpose-cast: dst[c*dld + r] = bf16(src[r*scols + c]); grid (scols/32, srows/32), block (32,8)
__global__ void tcast(const float* __restrict__ src, int scols, u16* __restrict__ dst, int dld) {
  __shared__ float tt[32][33];
  int c0 = blockIdx.x << 5, r0 = blockIdx.y << 5;
  int tx = threadIdx.x, ty = threadIdx.y;
#pragma unroll
  for (int j = 0; j < 4; ++j)
    tt[ty + j * 8][tx] = src[(size_t)(r0 + ty + j * 8) * scols + c0 + tx];
  __syncthreads();
#pragma unroll
  for (int j = 0; j < 4; ++j)
    dst[(size_t)(c0 + ty + j * 8) * dld + r0 + tx] = f2bf(tt[tx][ty + j * 8]);
}

// V part of qkv (cols [2560,3072)) -> vt[((b*8+g)*64 + d)*2048 + s]
__global__ void transpose_v(const u16* __restrict__ qkv, u16* __restrict__ vt) {
  __shared__ u16 tt[32][33];
  int c0 = blockIdx.x << 5, r0 = blockIdx.y << 5;   // c0: V col, r0: b*S+s row
  int tx = threadIdx.x, ty = threadIdx.y;
#pragma unroll
  for (int j = 0; j < 4; ++j)
    tt[ty + j * 8][tx] = qkv[(size_t)(r0 + ty + j * 8) * QKV_LD + 2560 + c0 + tx];
  __syncthreads();
#pragma unroll
  for (int j = 0; j < 4; ++j) {
    int c = c0 + ty + j * 8;              // V column -> (g,d)
    int rr = r0 + tx;                     // source row -> (b,s)
    int b = rr >> 11, s = rr & (SS - 1), g = c >> 6, d = c & 63;
    vt[(size_t)((((b << 3) + g) << 6) + d) * SS + s] = tt[tx][ty + j * 8];
  }
}

// ---------------------------------------------------------------------------
// C[M][N] = A[M][K] @ BT[N][K]^T   (bf16 in, fp32 acc), lda == K.
// 128x128 tile, BK=64, EIGHT waves (2m x 4n, each 64x32), 512 threads.
// Cf!=null: fp32 out + bias. else bf16 out.
// fc!=null (bf16 path only): FUSED RoPE epilogue — pair partner (col^1) lives
// in lane^1 (__shfl_xor(acc,1)); Q cols [0,2048) also pre-scaled by
// 1/sqrt(HD)*log2(e); V cols [2560,) pass through. RoPE applied to fp32 acc
// BEFORE bf16 quantization (matches reference ordering better than the old
// separate rope_k on quantized bf16). Runtime flag, not a template: avoids a
// second instantiation perturbing hot-loop regalloc (rule #19).
__global__ __launch_bounds__(512) void gemm_bt(const u16* __restrict__ A, const u16* __restrict__ BT,
                                               int K, u16* __restrict__ Cb, float* __restrict__ Cf,
                                               const float* __restrict__ bias, int ldc,
                                               const float* __restrict__ fc, const float* __restrict__ fs) {
  __shared__ alignas(16) u16 lds[2 * 128 * 64];
  u16* Al = lds;
  u16* Bl = lds + 128 * 64;
  const int t = threadIdx.x, w = t >> 6, lane = t & 63;
  const int q_l = lane & 15, gh = lane >> 4;
  const int m0 = blockIdx.y << 7, n0 = blockIdx.x << 7;
  const int wm = (w >> 2) << 6;        // 0 or 64
  const int wn = (w & 3) << 5;         // 0,32,64,96
  f32x4 acc[4][2] = {};

  for (int k0 = 0; k0 < K; k0 += 64) {
#pragma unroll
    for (int i = 0; i < 2; ++i) {
      int o = (i << 13) + (t << 4);                     // byte offset in 16KB tile
      int row = o >> 7;
      int cs = ((((o >> 4) & 7) ^ (row & 7)) << 4);     // pre-swizzled source block
      gload16((const char*)A + (((size_t)(m0 + row) * K + k0) << 1) + cs, (char*)Al + o);
      gload16((const char*)BT + (((size_t)(n0 + row) * K + k0) << 1) + cs, (char*)Bl + o);
    }
    __syncthreads();
#pragma unroll
    for (int kk = 0; kk < 64; kk += 32) {
      const int c = (kk >> 3) + gh;
      s16x8 af[4], bfr[2];
#pragma unroll
      for (int mi = 0; mi < 4; ++mi) af[mi] = lds_frag(Al, wm + (mi << 4) + q_l, c);
#pragma unroll
      for (int ni = 0; ni < 2; ++ni) bfr[ni] = lds_frag(Bl, wn + (ni << 4) + q_l, c);
#pragma unroll
      for (int mi = 0; mi < 4; ++mi)
#pragma unroll
        for (int ni = 0; ni < 2; ++ni)
          acc[mi][ni] = MFMA(af[mi], bfr[ni], acc[mi][ni]);
    }
    __syncthreads();
  }

  const int rbase = m0 + wm + (gh << 2);
  const int cbase = n0 + wn + q_l;
  if (Cf != nullptr) {
#pragma unroll
    for (int mi = 0; mi < 4; ++mi)
#pragma unroll
      for (int ni = 0; ni < 2; ++ni) {
        int col = cbase + (ni << 4);
        float bv = bias[col];
#pragma unroll
        for (int r = 0; r < 4; ++r)
          Cf[(size_t)(rbase + (mi << 4) + r) * ldc + col] = acc[mi][ni][r] + bv;
      }
  } else if (fc != nullptr) {
    // fused RoPE epilogue (QKV projection)
    const float SCLQ = 0.125f * 1.44269504f;   // 1/sqrt(HD) * log2(e)
    const bool odd = (lane & 1) != 0;
#pragma unroll
    for (int mi = 0; mi < 4; ++mi)
#pragma unroll
      for (int ni = 0; ni < 2; ++ni) {
        int col = cbase + (ni << 4);
        int i = (col & 63) >> 1;
        float sc = (col < 2048) ? SCLQ : 1.0f;
        bool dorope = (col < 2560);
#pragma unroll
        for (int r = 0; r < 4; ++r) {
          int row = rbase + (mi << 4) + r;
          int s = row & (SS - 1);
          float v = acc[mi][ni][r];
          float p = __shfl_xor(v, 1);          // pair partner (col^1)
          float cz = fc[s * 32 + i], sn = fs[s * 32 + i];
          float res = odd ? (p * sn + v * cz) : (v * cz - p * sn);
          res *= sc;
          if (!dorope) res = v;                // V columns: passthrough
          Cb[(size_t)row * ldc + col] = f2bf(res);
        }
      }
  } else {
#pragma unroll
    for (int mi = 0; mi < 4; ++mi)
#pragma unroll
      for (int ni = 0; ni < 2; ++ni) {
        int col = cbase + (ni << 4);
#pragma unroll
        for (int r = 0; r < 4; ++r)
          Cb[(size_t)(rbase + (mi << 4) + r) * ldc + col] = f2bf(acc[mi][ni][r]);
      }
  }
}

// ---------------------------------------------------------------------------
// Flash attention v9: swapped-operand QK^T + ones-MFMA l + max3 tree +
// reg-staged prefetch + double-buffered K/V (one barrier per tile) +
// balanced LPT. __launch_bounds__(256,4) pins regalloc (no spills).
__global__ __launch_bounds__(256, 4) void attn_k(const u16* __restrict__ qkv, const u16* __restrict__ vt,
                                                 u16* __restrict__ ctx) {
  __shared__ alignas(16) u16 sK[2][64 * 64];
  __shared__ alignas(16) u16 sV[2][64 * 64];
  __shared__ alignas(16) u16 sP[4][16 * 64];
  const int bid = blockIdx.x;
  const int qt = 31 - (bid >> 6);                 // balanced + LPT
  const int h = bid & 31, b = (bid >> 5) & 1;
  const int q0 = qt << 6, g = h >> 2;
  const int t = threadIdx.x, w = t >> 6, lane = t & 63;
  const int q_l = lane & 15, gh = lane >> 4;

  // all-ones bf16 fragment for the l-row MFMA
  const s16x8 ones = { (short)0x3F80, (short)0x3F80, (short)0x3F80, (short)0x3F80,
                       (short)0x3F80, (short)0x3F80, (short)0x3F80, (short)0x3F80 };

  // staging geometry: chunk i in 0..1, row = (i<<5) + (w<<3) + (lane>>3), blk = lane&7.
  const int srow = (w << 3) + (lane >> 3);        // row within chunk 0 (0..31)
  const int blk = lane & 7;                       // 16B block within 64-u16 row
  const int lw0 = (srow << 6) + ((blk ^ (lane >> 3)) << 3);   // row&7 == lane>>3
  const u16* kg = qkv + (size_t)((b << 11) + srow) * QKV_LD + 2048 + (g << 6) + (blk << 3);
  const u16* vg = vt + (size_t)((((b << 3) + g) << 6) + srow) * SS + (blk << 3);

  // Q fragment (B-frag for swapped QK: lane holds Q[q=lane&15][d=8*gh+e])
  const int qrow = (b << 11) + q0 + (w << 4) + q_l;
  const u16* qptr = qkv + (size_t)qrow * QKV_LD + (h << 6) + (gh << 3);
  s16x8 qa0 = *(const s16x8*)qptr;
  s16x8 qa1 = *(const s16x8*)(qptr + 32);

  f32x4 o[4] = {};
  f32x4 lacc = {};                                // l[q] in every reg (ones-row MFMA)
  float m1 = -INFINITY;
  const int myq = q0 + (w << 4) + q_l;            // this lane's q row

  // prologue: tile 0 regs -> LDS buf0 -> barrier
  s16x8 kr[2], vr[2];
#pragma unroll
  for (int i = 0; i < 2; ++i) {
    kr[i] = *(const s16x8*)(kg + (size_t)(i << 5) * QKV_LD);
    vr[i] = *(const s16x8*)(vg + (size_t)(i << 5) * SS);
  }
#pragma unroll
  for (int i = 0; i < 2; ++i) {
    *(s16x8*)(sK[0] + lw0 + (i << 11)) = kr[i];
    *(s16x8*)(sV[0] + lw0 + (i << 11)) = vr[i];
  }
  __syncthreads();

  for (int kt_i = 0; kt_i <= qt; ++kt_i) {
    const int k0 = kt_i << 6;
    const int cur = kt_i & 1;
    const u16* Kl = sK[cur];
    const u16* Vl = sV[cur];
    // issue next-tile global loads early; latency hides under this tile's compute
    if (kt_i < qt) {
      const int kn = k0 + 64;
#pragma unroll
      for (int i = 0; i < 2; ++i) {
        kr[i] = *(const s16x8*)(kg + (size_t)(kn + (i << 5)) * QKV_LD);
        vr[i] = *(const s16x8*)(vg + (size_t)(i << 5) * SS + kn);
      }
    }

    // S^T = K Q^T (64k x 16q per wave); lane: q = lane&15, k = nc*16 + gh*4 + r
    f32x4 sacc[4];
    __builtin_amdgcn_s_setprio(1);
#pragma unroll
    for (int nc = 0; nc < 4; ++nc) {
      f32x4 a = {};
      a = MFMA(lds_frag(Kl, (nc << 4) + q_l, gh), qa0, a);
      a = MFMA(lds_frag(Kl, (nc << 4) + q_l, 4 + gh), qa1, a);
      sacc[nc] = a;
    }
    __builtin_amdgcn_s_setprio(0);

    // causal mask on the diagonal tile only (Q already carries the scale)
    float pv[4][4];
    if (kt_i == qt) {
#pragma unroll
      for (int nc = 0; nc < 4; ++nc) {
        int kb = k0 + (nc << 4) + (gh << 2);
#pragma unroll
        for (int r = 0; r < 4; ++r) {
          float v = sacc[nc][r];
          if (kb + r > myq) v = -INFINITY;
          pv[nc][r] = v;
        }
      }
    } else {
#pragma unroll
      for (int nc = 0; nc < 4; ++nc)
#pragma unroll
        for (int r = 0; r < 4; ++r)
          pv[nc][r] = sacc[nc][r];
    }

    // lane-local tile max (max3-friendly tree) + defer-max check
    float ta = fmaxf(fmaxf(pv[0][0], pv[0][1]), pv[0][2]);
    float tb = fmaxf(fmaxf(pv[0][3], pv[1][0]), pv[1][1]);
    float tc = fmaxf(fmaxf(pv[1][2], pv[1][3]), pv[2][0]);
    float td = fmaxf(fmaxf(pv[2][1], pv[2][2]), pv[2][3]);
    float te = fmaxf(fmaxf(pv[3][0], pv[3][1]), pv[3][2]);
    float tmax = fmaxf(fmaxf(fmaxf(ta, tb), fmaxf(tc, td)), fmaxf(te, pv[3][3]));
    if (__any(tmax > m1 + 8.f)) {
      // row max over all 64 k (across the 4 lane-groups), uniform per q
      float rmax = tmax;
      rmax = fmaxf(rmax, __shfl_xor(rmax, 16));
      rmax = fmaxf(rmax, __shfl_xor(rmax, 32));
      float mn = fmaxf(m1, rmax);
      float alpha = exp2f(m1 - mn);
      m1 = mn;
#pragma unroll
      for (int r = 0; r < 4; ++r) lacc[r] *= alpha;
#pragma unroll
      for (int dc = 0; dc < 4; ++dc)
#pragma unroll
        for (int r = 0; r < 4; ++r) o[dc][r] *= alpha;
    }

    // P = exp2(S' - m)  (l comes from the ones-row MFMA below)
#pragma unroll
    for (int nc = 0; nc < 4; ++nc)
#pragma unroll
      for (int r = 0; r < 4; ++r)
        pv[nc][r] = exp2f(pv[nc][r] - m1);

    // P^T -> per-wave LDS [16 q][64 k], k-contiguous: one b64 per nc
    u16* pb = sP[w];
#pragma unroll
    for (int nc = 0; nc < 4; ++nc) {
      u32x2 pw;
      pw[0] = cvtpk(pv[nc][0], pv[nc][1]);
      pw[1] = cvtpk(pv[nc][2], pv[nc][3]);
      int byte = (q_l << 7) + (((((nc << 1) + (gh >> 1)) ^ (q_l & 7)) << 4)) + ((gh & 1) << 3);
      *(u32x2*)((char*)pb + byte) = pw;
    }
    asm volatile("s_waitcnt lgkmcnt(0)" ::: "memory");   // intra-wave P write->read
    __builtin_amdgcn_sched_barrier(0);

    // O^T += V^T P^T ; l += 1^T P^T (matrix pipe)
    s16x8 pa0 = lds_frag(pb, q_l, gh);
    s16x8 pa1 = lds_frag(pb, q_l, 4 + gh);
    __builtin_amdgcn_s_setprio(1);
#pragma unroll
    for (int dc = 0; dc < 4; ++dc) {
      o[dc] = MFMA(lds_frag(Vl, (dc << 4) + q_l, gh), pa0, o[dc]);
      o[dc] = MFMA(lds_frag(Vl, (dc << 4) + q_l, 4 + gh), pa1, o[dc]);
    }
    lacc = MFMA(ones, pa0, lacc);
    lacc = MFMA(ones, pa1, lacc);
    __builtin_amdgcn_s_setprio(0);

    // publish next tile into the other buffer (no WAR: nobody reads it now)
    if (kt_i < qt) {
#pragma unroll
      for (int i = 0; i < 2; ++i) {
        *(s16x8*)(sK[cur ^ 1] + lw0 + (i << 11)) = kr[i];
        *(s16x8*)(sV[cur ^ 1] + lw0 + (i << 11)) = vr[i];
      }
    }
    __syncthreads();                 // single rendezvous: closes reads + publishes writes
  }

  // epilogue: lacc[r] all hold l[q]; ctx row is fixed per lane (q)
  float inv = 1.0f / lacc[0];
  u16* crow = ctx + (size_t)((b << 11) + myq) * DD + (h << 6) + (gh << 2);
#pragma unroll
  for (int dc = 0; dc < 4; ++dc) {
    u32x2 ov;
    ov[0] = cvtpk(o[dc][0] * inv, o[dc][1] * inv);
    ov[1] = cvtpk(o[dc][2] * inv, o[dc][3] * inv);
    *(u32x2*)(crow + (dc << 4)) = ov;
  }
}

// ---------------------------------------------------------------------------
extern "C" void kernel_launch(void* const* d_in, const int* in_sizes, int n_in,
                              void* d_out, int out_size, void* d_ws, size_t ws_size,
                              hipStream_t stream) {
  const float* x  = (const float*)d_in[0];
  const float* Wq = (const float*)d_in[1];
  const float* Wk = (const float*)d_in[2];
  const float* Wv = (const float*)d_in[3];
  const float* Wo = (const float*)d_in[4];
  const float* bo = (const float*)d_in[5];
  const float* fc = (const float*)d_in[6];
  const float* fs = (const float*)d_in[7];
  float* out = (float*)d_out;

  // workspace layout (u16 units):
  u16* ws   = (u16*)d_ws;
  u16* xb   = ws;                      // 8,388,608  (x bf16; reused as ctx)
  u16* wT   = xb + 8388608;            // 6,291,456  (W_qkv^T; reused as W_o^T)
  u16* qkv  = wT + 6291456;            // 12,582,912 (Q|K|V, ld 3072)
  u16* vt   = qkv + 12582912;          // 2,097,152  (V^T per (b,g): [64][2048])
  u16* ctx  = xb;
  u16* woT  = wT;

  dim3 b32(32, 8, 1);

  // 1. casts / transposes of weights + x
  cast_bf<<<8192, 256, 0, stream>>>(x, xb);
  tcast<<<dim3(64, 64), b32, 0, stream>>>(Wq, 2048, wT, 2048);
  tcast<<<dim3(16, 64), b32, 0, stream>>>(Wk, 512, wT + (size_t)2048 * 2048, 2048);
  tcast<<<dim3(16, 64), b32, 0, stream>>>(Wv, 512, wT + (size_t)2560 * 2048, 2048);

  // 2. fused QKV projection WITH RoPE epilogue (Q pre-scaled, K roped, V raw):
  //    [4096][2048] @ [3072][2048]^T -> qkv bf16
  gemm_bt<<<dim3(24, 32), 512, 0, stream>>>(xb, wT, 2048, qkv, nullptr, nullptr, QKV_LD, fc, fs);

  // 3. W_o^T
  tcast<<<dim3(64, 64), b32, 0, stream>>>(Wo, 2048, woT, 2048);

  // 4. transpose V
  transpose_v<<<dim3(16, 128), b32, 0, stream>>>(qkv, vt);

  // 5. flash attention -> ctx bf16 [4096][2048]
  attn_k<<<2048, 256, 0, stream>>>(qkv, vt, ctx);

  // 6. output projection + bias -> fp32 d_out
  gemm_bt<<<dim3(16, 32), 512, 0, stream>>>(ctx, woT, 2048, nullptr, out, bo, 2048, nullptr, nullptr);
}

// Round 21
// 200.932 us; speedup vs baseline: 1.1461x; 1.0277x over previous
//
#include <hip/hip_runtime.h>
#include <hip/hip_bf16.h>

// Problem constants: B=2, S=2048, D=2048, H=32, KVH=8, HD=64, N_REP=4
#define BB 2
#define SS 2048
#define DD 2048
#define HH 32
#define KVH 8
#define HD 64
#define QKV_LD 3072   // Q(2048) | K(512) | V(512)

typedef unsigned short u16;
typedef unsigned int u32;
typedef __attribute__((ext_vector_type(8))) short s16x8;   // bf16x8 MFMA fragment (4 VGPRs)
typedef __attribute__((ext_vector_type(4))) float f32x4;   // MFMA accumulator
typedef __attribute__((ext_vector_type(4))) u16 u16x4;
typedef __attribute__((ext_vector_type(2))) u32 u32x2;

#define MFMA(a, b, c) __builtin_amdgcn_mfma_f32_16x16x32_bf16((a), (b), (c), 0, 0, 0)

__device__ __forceinline__ u16 f2bf(float f) {
  union { float f; u32 u; } x; x.f = f;
  u32 r = x.u + 0x7fffu + ((x.u >> 16) & 1u);  // round-to-nearest-even
  return (u16)(r >> 16);
}
__device__ __forceinline__ float bf2f(u32 u) {
  union { u32 u; float f; } x; x.u = u << 16;
  return x.f;
}
// HW packed f32x2 -> bf16x2 (RTNE), lo=a, hi=b
__device__ __forceinline__ u32 cvtpk(float a, float b) {
  u32 r;
  asm("v_cvt_pk_bf16_f32 %0, %1, %2" : "=v"(r) : "v"(a), "v"(b));
  return r;
}

// async global->LDS, 16B per lane. dest must be (wave-uniform base + lane*16).
__device__ __forceinline__ void gload16(const void* g, void* l) {
  __builtin_amdgcn_global_load_lds((const __attribute__((address_space(1))) unsigned int*)g,
                                   (__attribute__((address_space(3))) unsigned int*)l, 16, 0, 0);
}

// Read one bf16x8 MFMA fragment from a [rows][64] bf16 LDS tile with the
// G4 XOR swizzle (16B block index ^= row&7). c = 16B-block index (k/8).
__device__ __forceinline__ s16x8 lds_frag(const u16* base, int row, int c) {
  return *(const s16x8*)(base + (row << 6) + (((c ^ (row & 7)) << 3)));
}

// ---------------------------------------------------------------------------
// cast fp32 -> bf16, 4 elems/thread, exact grid (at HBM roofline: 96MB/15us)
__global__ void cast_bf(const float* __restrict__ s, u16* __restrict__ d) {
  int i = blockIdx.x * 256 + threadIdx.x;
  float4 v = ((const float4*)s)[i];
  u16x4 o;
  o[0] = f2bf(v.x); o[1] = f2bf(v.y); o[2] = f2bf(v.z); o[3] = f2bf(v.w);
  ((u16x4*)d)[i] = o;
}

// transpose-cast: dst[c*dld + r] = bf16(src[r*scols + c]); grid (scols/32, srows/32), block (32,8)
__global__ void tcast(const float* __restrict__ src, int scols, u16* __restrict__ dst, int dld) {
  __shared__ float tt[32][33];
  int c0 = blockIdx.x << 5, r0 = blockIdx.y << 5;
  int tx = threadIdx.x, ty = threadIdx.y;
#pragma unroll
  for (int j = 0; j < 4; ++j)
    tt[ty + j * 8][tx] = src[(size_t)(r0 + ty + j * 8) * scols + c0 + tx];
  __syncthreads();
#pragma unroll
  for (int j = 0; j < 4; ++j)
    dst[(size_t)(c0 + ty + j * 8) * dld + r0 + tx] = f2bf(tt[tx][ty + j * 8]);
}

// ---------------------------------------------------------------------------
// C[M][N] = A[M][K] @ BT[N][K]^T   (bf16 in, fp32 acc), lda == K.
// 128x128 tile, BK=64, EIGHT waves (2m x 4n, each 64x32), 512 threads.
// Cf!=null: fp32 out + bias.
// fc!=null (bf16 path): FUSED RoPE epilogue for Q/K tiles (pair partner col^1
// lives in lane^1 -> __shfl_xor(acc,1); Q cols [0,2048) pre-scaled by
// 1/sqrt(HD)*log2(e)); V tiles (n0>=2560) are written DIRECTLY TRANSPOSED to
// vtp[((b*8+g)*64+d)*2048 + s] (the r-loop's 4 rows are 4 consecutive s ->
// one 8B store; transpose_v dispatch eliminated). Tile grid splits exactly at
// col 2048/2560, so each tile is purely Q, K, or V (block-uniform branch).
__global__ __launch_bounds__(512) void gemm_bt(const u16* __restrict__ A, const u16* __restrict__ BT,
                                               int K, u16* __restrict__ Cb, float* __restrict__ Cf,
                                               const float* __restrict__ bias, int ldc,
                                               const float* __restrict__ fc, const float* __restrict__ fs,
                                               u16* __restrict__ vtp) {
  __shared__ alignas(16) u16 lds[2 * 128 * 64];
  u16* Al = lds;
  u16* Bl = lds + 128 * 64;
  const int t = threadIdx.x, w = t >> 6, lane = t & 63;
  const int q_l = lane & 15, gh = lane >> 4;
  const int m0 = blockIdx.y << 7, n0 = blockIdx.x << 7;
  const int wm = (w >> 2) << 6;        // 0 or 64
  const int wn = (w & 3) << 5;         // 0,32,64,96
  f32x4 acc[4][2] = {};

  for (int k0 = 0; k0 < K; k0 += 64) {
#pragma unroll
    for (int i = 0; i < 2; ++i) {
      int o = (i << 13) + (t << 4);                     // byte offset in 16KB tile
      int row = o >> 7;
      int cs = ((((o >> 4) & 7) ^ (row & 7)) << 4);     // pre-swizzled source block
      gload16((const char*)A + (((size_t)(m0 + row) * K + k0) << 1) + cs, (char*)Al + o);
      gload16((const char*)BT + (((size_t)(n0 + row) * K + k0) << 1) + cs, (char*)Bl + o);
    }
    __syncthreads();
#pragma unroll
    for (int kk = 0; kk < 64; kk += 32) {
      const int c = (kk >> 3) + gh;
      s16x8 af[4], bfr[2];
#pragma unroll
      for (int mi = 0; mi < 4; ++mi) af[mi] = lds_frag(Al, wm + (mi << 4) + q_l, c);
#pragma unroll
      for (int ni = 0; ni < 2; ++ni) bfr[ni] = lds_frag(Bl, wn + (ni << 4) + q_l, c);
#pragma unroll
      for (int mi = 0; mi < 4; ++mi)
#pragma unroll
        for (int ni = 0; ni < 2; ++ni)
          acc[mi][ni] = MFMA(af[mi], bfr[ni], acc[mi][ni]);
    }
    __syncthreads();
  }

  const int rbase = m0 + wm + (gh << 2);
  const int cbase = n0 + wn + q_l;
  if (Cf != nullptr) {
#pragma unroll
    for (int mi = 0; mi < 4; ++mi)
#pragma unroll
      for (int ni = 0; ni < 2; ++ni) {
        int col = cbase + (ni << 4);
        float bv = bias[col];
#pragma unroll
        for (int r = 0; r < 4; ++r)
          Cf[(size_t)(rbase + (mi << 4) + r) * ldc + col] = acc[mi][ni][r] + bv;
      }
  } else if (fc != nullptr) {
    if (n0 >= 2560) {
      // V tile: write transposed directly to vt (no rope/scale)
      const int b = rbase >> 11;
#pragma unroll
      for (int mi = 0; mi < 4; ++mi) {
        int s0 = (rbase + (mi << 4)) & (SS - 1);
#pragma unroll
        for (int ni = 0; ni < 2; ++ni) {
          int cv = cbase + (ni << 4) - 2560;   // V column -> (g,d)
          int g = cv >> 6, d = cv & 63;
          u16x4 pk;
#pragma unroll
          for (int r = 0; r < 4; ++r) pk[r] = f2bf(acc[mi][ni][r]);
          *(u16x4*)(vtp + (size_t)((((b << 3) + g) << 6) + d) * SS + s0) = pk;
        }
      }
    } else {
      // Q/K tile: fused RoPE epilogue
      const float SCLQ = 0.125f * 1.44269504f;   // 1/sqrt(HD) * log2(e)
      const bool odd = (lane & 1) != 0;
#pragma unroll
      for (int mi = 0; mi < 4; ++mi)
#pragma unroll
        for (int ni = 0; ni < 2; ++ni) {
          int col = cbase + (ni << 4);
          int i = (col & 63) >> 1;
          float sc = (col < 2048) ? SCLQ : 1.0f;
#pragma unroll
          for (int r = 0; r < 4; ++r) {
            int row = rbase + (mi << 4) + r;
            int s = row & (SS - 1);
            float v = acc[mi][ni][r];
            float p = __shfl_xor(v, 1);          // pair partner (col^1)
            float cz = fc[s * 32 + i], sn = fs[s * 32 + i];
            float res = (odd ? (p * sn + v * cz) : (v * cz - p * sn)) * sc;
            Cb[(size_t)row * ldc + col] = f2bf(res);
          }
        }
    }
  } else {
#pragma unroll
    for (int mi = 0; mi < 4; ++mi)
#pragma unroll
      for (int ni = 0; ni < 2; ++ni) {
        int col = cbase + (ni << 4);
#pragma unroll
        for (int r = 0; r < 4; ++r)
          Cb[(size_t)(rbase + (mi << 4) + r) * ldc + col] = f2bf(acc[mi][ni][r]);
      }
  }
}

// ---------------------------------------------------------------------------
// Flash attention v9: swapped-operand QK^T + ones-MFMA l + max3 tree +
// reg-staged prefetch + double-buffered K/V (one barrier per tile) +
// balanced LPT. __launch_bounds__(256,4) pins regalloc (no spills).
__global__ __launch_bounds__(256, 4) void attn_k(const u16* __restrict__ qkv, const u16* __restrict__ vt,
                                                 u16* __restrict__ ctx) {
  __shared__ alignas(16) u16 sK[2][64 * 64];
  __shared__ alignas(16) u16 sV[2][64 * 64];
  __shared__ alignas(16) u16 sP[4][16 * 64];
  const int bid = blockIdx.x;
  const int qt = 31 - (bid >> 6);                 // balanced + LPT
  const int h = bid & 31, b = (bid >> 5) & 1;
  const int q0 = qt << 6, g = h >> 2;
  const int t = threadIdx.x, w = t >> 6, lane = t & 63;
  const int q_l = lane & 15, gh = lane >> 4;

  // all-ones bf16 fragment for the l-row MFMA
  const s16x8 ones = { (short)0x3F80, (short)0x3F80, (short)0x3F80, (short)0x3F80,
                       (short)0x3F80, (short)0x3F80, (short)0x3F80, (short)0x3F80 };

  // staging geometry: chunk i in 0..1, row = (i<<5) + (w<<3) + (lane>>3), blk = lane&7.
  const int srow = (w << 3) + (lane >> 3);        // row within chunk 0 (0..31)
  const int blk = lane & 7;                       // 16B block within 64-u16 row
  const int lw0 = (srow << 6) + ((blk ^ (lane >> 3)) << 3);   // row&7 == lane>>3
  const u16* kg = qkv + (size_t)((b << 11) + srow) * QKV_LD + 2048 + (g << 6) + (blk << 3);
  const u16* vg = vt + (size_t)((((b << 3) + g) << 6) + srow) * SS + (blk << 3);

  // Q fragment (B-frag for swapped QK: lane holds Q[q=lane&15][d=8*gh+e])
  const int qrow = (b << 11) + q0 + (w << 4) + q_l;
  const u16* qptr = qkv + (size_t)qrow * QKV_LD + (h << 6) + (gh << 3);
  s16x8 qa0 = *(const s16x8*)qptr;
  s16x8 qa1 = *(const s16x8*)(qptr + 32);

  f32x4 o[4] = {};
  f32x4 lacc = {};                                // l[q] in every reg (ones-row MFMA)
  float m1 = -INFINITY;
  const int myq = q0 + (w << 4) + q_l;            // this lane's q row

  // prologue: tile 0 regs -> LDS buf0 -> barrier
  s16x8 kr[2], vr[2];
#pragma unroll
  for (int i = 0; i < 2; ++i) {
    kr[i] = *(const s16x8*)(kg + (size_t)(i << 5) * QKV_LD);
    vr[i] = *(const s16x8*)(vg + (size_t)(i << 5) * SS);
  }
#pragma unroll
  for (int i = 0; i < 2; ++i) {
    *(s16x8*)(sK[0] + lw0 + (i << 11)) = kr[i];
    *(s16x8*)(sV[0] + lw0 + (i << 11)) = vr[i];
  }
  __syncthreads();

  for (int kt_i = 0; kt_i <= qt; ++kt_i) {
    const int k0 = kt_i << 6;
    const int cur = kt_i & 1;
    const u16* Kl = sK[cur];
    const u16* Vl = sV[cur];
    // issue next-tile global loads early; latency hides under this tile's compute
    if (kt_i < qt) {
      const int kn = k0 + 64;
#pragma unroll
      for (int i = 0; i < 2; ++i) {
        kr[i] = *(const s16x8*)(kg + (size_t)(kn + (i << 5)) * QKV_LD);
        vr[i] = *(const s16x8*)(vg + (size_t)(i << 5) * SS + kn);
      }
    }

    // S^T = K Q^T (64k x 16q per wave); lane: q = lane&15, k = nc*16 + gh*4 + r
    f32x4 sacc[4];
    __builtin_amdgcn_s_setprio(1);
#pragma unroll
    for (int nc = 0; nc < 4; ++nc) {
      f32x4 a = {};
      a = MFMA(lds_frag(Kl, (nc << 4) + q_l, gh), qa0, a);
      a = MFMA(lds_frag(Kl, (nc << 4) + q_l, 4 + gh), qa1, a);
      sacc[nc] = a;
    }
    __builtin_amdgcn_s_setprio(0);

    // causal mask on the diagonal tile only (Q already carries the scale)
    float pv[4][4];
    if (kt_i == qt) {
#pragma unroll
      for (int nc = 0; nc < 4; ++nc) {
        int kb = k0 + (nc << 4) + (gh << 2);
#pragma unroll
        for (int r = 0; r < 4; ++r) {
          float v = sacc[nc][r];
          if (kb + r > myq) v = -INFINITY;
          pv[nc][r] = v;
        }
      }
    } else {
#pragma unroll
      for (int nc = 0; nc < 4; ++nc)
#pragma unroll
        for (int r = 0; r < 4; ++r)
          pv[nc][r] = sacc[nc][r];
    }

    // lane-local tile max (max3-friendly tree) + defer-max check
    float ta = fmaxf(fmaxf(pv[0][0], pv[0][1]), pv[0][2]);
    float tb = fmaxf(fmaxf(pv[0][3], pv[1][0]), pv[1][1]);
    float tc = fmaxf(fmaxf(pv[1][2], pv[1][3]), pv[2][0]);
    float td = fmaxf(fmaxf(pv[2][1], pv[2][2]), pv[2][3]);
    float te = fmaxf(fmaxf(pv[3][0], pv[3][1]), pv[3][2]);
    float tmax = fmaxf(fmaxf(fmaxf(ta, tb), fmaxf(tc, td)), fmaxf(te, pv[3][3]));
    if (__any(tmax > m1 + 8.f)) {
      // row max over all 64 k (across the 4 lane-groups), uniform per q
      float rmax = tmax;
      rmax = fmaxf(rmax, __shfl_xor(rmax, 16));
      rmax = fmaxf(rmax, __shfl_xor(rmax, 32));
      float mn = fmaxf(m1, rmax);
      float alpha = exp2f(m1 - mn);
      m1 = mn;
#pragma unroll
      for (int r = 0; r < 4; ++r) lacc[r] *= alpha;
#pragma unroll
      for (int dc = 0; dc < 4; ++dc)
#pragma unroll
        for (int r = 0; r < 4; ++r) o[dc][r] *= alpha;
    }

    // P = exp2(S' - m)  (l comes from the ones-row MFMA below)
#pragma unroll
    for (int nc = 0; nc < 4; ++nc)
#pragma unroll
      for (int r = 0; r < 4; ++r)
        pv[nc][r] = exp2f(pv[nc][r] - m1);

    // P^T -> per-wave LDS [16 q][64 k], k-contiguous: one b64 per nc
    u16* pb = sP[w];
#pragma unroll
    for (int nc = 0; nc < 4; ++nc) {
      u32x2 pw;
      pw[0] = cvtpk(pv[nc][0], pv[nc][1]);
      pw[1] = cvtpk(pv[nc][2], pv[nc][3]);
      int byte = (q_l << 7) + (((((nc << 1) + (gh >> 1)) ^ (q_l & 7)) << 4)) + ((gh & 1) << 3);
      *(u32x2*)((char*)pb + byte) = pw;
    }
    asm volatile("s_waitcnt lgkmcnt(0)" ::: "memory");   // intra-wave P write->read
    __builtin_amdgcn_sched_barrier(0);

    // O^T += V^T P^T ; l += 1^T P^T (matrix pipe)
    s16x8 pa0 = lds_frag(pb, q_l, gh);
    s16x8 pa1 = lds_frag(pb, q_l, 4 + gh);
    __builtin_amdgcn_s_setprio(1);
#pragma unroll
    for (int dc = 0; dc < 4; ++dc) {
      o[dc] = MFMA(lds_frag(Vl, (dc << 4) + q_l, gh), pa0, o[dc]);
      o[dc] = MFMA(lds_frag(Vl, (dc << 4) + q_l, 4 + gh), pa1, o[dc]);
    }
    lacc = MFMA(ones, pa0, lacc);
    lacc = MFMA(ones, pa1, lacc);
    __builtin_amdgcn_s_setprio(0);

    // publish next tile into the other buffer (no WAR: nobody reads it now)
    if (kt_i < qt) {
#pragma unroll
      for (int i = 0; i < 2; ++i) {
        *(s16x8*)(sK[cur ^ 1] + lw0 + (i << 11)) = kr[i];
        *(s16x8*)(sV[cur ^ 1] + lw0 + (i << 11)) = vr[i];
      }
    }
    __syncthreads();                 // single rendezvous: closes reads + publishes writes
  }

  // epilogue: lacc[r] all hold l[q]; ctx row is fixed per lane (q)
  float inv = 1.0f / lacc[0];
  u16* crow = ctx + (size_t)((b << 11) + myq) * DD + (h << 6) + (gh << 2);
#pragma unroll
  for (int dc = 0; dc < 4; ++dc) {
    u32x2 ov;
    ov[0] = cvtpk(o[dc][0] * inv, o[dc][1] * inv);
    ov[1] = cvtpk(o[dc][2] * inv, o[dc][3] * inv);
    *(u32x2*)(crow + (dc << 4)) = ov;
  }
}

// ---------------------------------------------------------------------------
extern "C" void kernel_launch(void* const* d_in, const int* in_sizes, int n_in,
                              void* d_out, int out_size, void* d_ws, size_t ws_size,
                              hipStream_t stream) {
  const float* x  = (const float*)d_in[0];
  const float* Wq = (const float*)d_in[1];
  const float* Wk = (const float*)d_in[2];
  const float* Wv = (const float*)d_in[3];
  const float* Wo = (const float*)d_in[4];
  const float* bo = (const float*)d_in[5];
  const float* fc = (const float*)d_in[6];
  const float* fs = (const float*)d_in[7];
  float* out = (float*)d_out;

  // workspace layout (u16 units):
  u16* ws   = (u16*)d_ws;
  u16* xb   = ws;                      // 8,388,608  (x bf16; reused as ctx)
  u16* wT   = xb + 8388608;            // 6,291,456  (W_qkv^T; reused as W_o^T)
  u16* qkv  = wT + 6291456;            // 12,582,912 (Q|K roped; V cols unused)
  u16* vt   = qkv + 12582912;          // 2,097,152  (V^T per (b,g): [64][2048])
  u16* ctx  = xb;
  u16* woT  = wT;

  dim3 b32(32, 8, 1);

  // 1. casts / transposes of weights + x
  cast_bf<<<8192, 256, 0, stream>>>(x, xb);
  tcast<<<dim3(64, 64), b32, 0, stream>>>(Wq, 2048, wT, 2048);
  tcast<<<dim3(16, 64), b32, 0, stream>>>(Wk, 512, wT + (size_t)2048 * 2048, 2048);
  tcast<<<dim3(16, 64), b32, 0, stream>>>(Wv, 512, wT + (size_t)2560 * 2048, 2048);

  // 2. fused QKV projection: RoPE epilogue on Q/K tiles, V tiles written
  //    directly transposed to vt. [4096][2048] @ [3072][2048]^T
  gemm_bt<<<dim3(24, 32), 512, 0, stream>>>(xb, wT, 2048, qkv, nullptr, nullptr, QKV_LD, fc, fs, vt);

  // 3. W_o^T
  tcast<<<dim3(64, 64), b32, 0, stream>>>(Wo, 2048, woT, 2048);

  // 4. flash attention -> ctx bf16 [4096][2048]
  attn_k<<<2048, 256, 0, stream>>>(qkv, vt, ctx);

  // 5. output projection + bias -> fp32 d_out
  gemm_bt<<<dim3(16, 32), 512, 0, stream>>>(ctx, woT, 2048, nullptr, out, bo, 2048, nullptr, nullptr, nullptr);
}